// Round 1
// baseline (244.395 us; speedup 1.0000x reference)
//
#include <hip/hip_runtime.h>
#include <stdint.h>

typedef unsigned short u16;
typedef __attribute__((ext_vector_type(8))) short frag8;   // 8 bf16 in 4 VGPRs
typedef __attribute__((ext_vector_type(4))) float f32x4;
typedef __attribute__((ext_vector_type(4))) unsigned short u16x4;
typedef __attribute__((ext_vector_type(2))) unsigned int u32x2;

#define MFMA_BF16(a,b,c) __builtin_amdgcn_mfma_f32_16x16x32_bf16((a),(b),(c),0,0,0)
#define SMSCALE 0.18033688011112042f  /* (1/sqrt(64)) * log2(e) */
#define EXP2R(x) __builtin_amdgcn_exp2f(x)   /* raw v_exp_f32, no ocml fixup */

__device__ __forceinline__ u16 f2bf(float f) {
  union { float f; uint32_t u; } c; c.f = f;
  uint32_t u = c.u;
  uint32_t r = (u + 0x7fffu + ((u >> 16) & 1u)) >> 16;
  return (u16)r;
}

// pack two floats' bf16 (round-half-up) into one u32: low=a, high=b
__device__ __forceinline__ uint32_t pack_bf16(float a, float b) {
  uint32_t au = __float_as_uint(a) + 0x8000u;
  uint32_t bu = __float_as_uint(b) + 0x8000u;
  return __builtin_amdgcn_perm(bu, au, 0x07060302u);
}
// truncating pack (1 instr): P in [0,1], proportional bias cancels in O=SumpV/Sump
__device__ __forceinline__ uint32_t pack_bf16_trunc(float a, float b) {
  return __builtin_amdgcn_perm(__float_as_uint(b), __float_as_uint(a), 0x07060302u);
}

__device__ __forceinline__ void async16(const void* g, void* l) {
  __builtin_amdgcn_global_load_lds((const __attribute__((address_space(1))) void*)g,
                                   (__attribute__((address_space(3))) void*)l,
                                   16, 0, 0);
}

// ---------------- convert x (fp32 -> bf16) ----------------
__global__ __launch_bounds__(256) void k_convert_x(const float4* __restrict__ x,
                                                   u16* __restrict__ xb) {
  int i = blockIdx.x * 256 + threadIdx.x;
  float4 v = x[i];
  u16x4 o;
  o.x = f2bf(v.x); o.y = f2bf(v.y); o.z = f2bf(v.z); o.w = f2bf(v.w);
  *(u16x4*)(xb + (size_t)i * 4) = o;
}

// ---------------- transpose all 4 W (fp32 [k][n] -> bf16 [n][k]) ----------------
__global__ __launch_bounds__(256) void k_transpose_w4(
    const float* __restrict__ W0, const float* __restrict__ W1,
    const float* __restrict__ W2, const float* __restrict__ W3,
    u16* __restrict__ D0, u16* __restrict__ D1,
    u16* __restrict__ D2, u16* __restrict__ D3) {
  __shared__ float tile[64][65];
  const int z = blockIdx.z;
  const float* src = (z == 0) ? W0 : (z == 1) ? W1 : (z == 2) ? W2 : W3;
  u16* dst = (z == 0) ? D0 : (z == 1) ? D1 : (z == 2) ? D2 : D3;
  const int bx = blockIdx.x * 64;  // k base
  const int by = blockIdx.y * 64;  // n base
  const int t = threadIdx.x;
  const int tc = (t & 15) * 4;
  const int tr = t >> 4;
  #pragma unroll
  for (int p = 0; p < 4; ++p) {
    int r = tr + p * 16;
    float4 v = *(const float4*)(src + (size_t)(bx + r) * 1024 + by + tc);
    tile[r][tc + 0] = v.x; tile[r][tc + 1] = v.y;
    tile[r][tc + 2] = v.z; tile[r][tc + 3] = v.w;
  }
  __syncthreads();
  #pragma unroll
  for (int p = 0; p < 4; ++p) {
    int r = tr + p * 16;
    u16x4 o;
    o.x = f2bf(tile[tc + 0][r]);
    o.y = f2bf(tile[tc + 1][r]);
    o.z = f2bf(tile[tc + 2][r]);
    o.w = f2bf(tile[tc + 3][r]);
    *(u16x4*)(dst + (size_t)(by + r) * 1024 + bx + tc) = o;
  }
}

// ---------------- shared phase-pipelined GEMM core ----------------
// BM=256 x BN=128, BK=64, 512 threads = 8 waves (4M x 2N), 64x64 out per wave.
// Triple-buffered LDS (3 x 48KB), 2 phases per K-tile, counted vmcnt(6) once per
// K-tile (never drained to 0 in the main loop) -> T3+T4; setprio around MFMA -> T5;
// both-sides XOR swizzle (pre-swizzled global src, swizzled ds_read) -> T2.
// Per phase: 8x ds_read_b128 + 3x global_load_lds + barrier + lgkmcnt(0) + 16 MFMA
// (same per-phase MFMA density as the verified 256^2 8-phase template).
__device__ __forceinline__ void gemm_core_256x128(
    const u16* __restrict__ Ag,   // [M][1024] bf16, rows m0..m0+255
    const u16* __restrict__ Bg,   // [N][1024] bf16 (n-major), rows n0..n0+127
    int m0, int n0, u16* smem, f32x4 (&acc)[4][4]) {
  const int t = threadIdx.x, lane = t & 63, wv = t >> 6;
  const int lm = lane & 15, quad = lane >> 4;
  const int wr = wv >> 1, wc = wv & 1;

  // per-thread staging sources (k advances by 64 u16 per tile); LDS dst is
  // wave-uniform base (HW appends lane*16)
  const u16* sA[4]; int dA[4];
  #pragma unroll
  for (int it = 0; it < 4; ++it) {
    int chunk = it * 512 + t;          // A: 2048 16B chunks
    int r = chunk >> 3;                // row 0..255
    int sc = ((chunk & 7) ^ (r & 7)) * 8;
    sA[it] = Ag + (size_t)(m0 + r) * 1024 + sc;
    dA[it] = (it * 512 + wv * 64) * 8;
  }
  const u16* sB[2]; int dB[2];
  #pragma unroll
  for (int it = 0; it < 2; ++it) {
    int chunk = it * 512 + t;          // B: 1024 16B chunks
    int r = chunk >> 3;                // row 0..127
    int sc = ((chunk & 7) ^ (r & 7)) * 8;
    sB[it] = Bg + (size_t)(n0 + r) * 1024 + sc;
    dB[it] = 16384 + (it * 512 + wv * 64) * 8;
  }

  // fragment LDS offsets (u16 units), kslot = kk*4+quad, XOR-swizzled by row
  int offA[2][4], offB[2][4];
  #pragma unroll
  for (int kk = 0; kk < 2; ++kk) {
    #pragma unroll
    for (int i = 0; i < 4; ++i) {
      int rowa = wr * 64 + i * 16 + lm;
      offA[kk][i] = rowa * 64 + (((kk * 4 + quad) ^ (rowa & 7)) * 8);
      int rowb = wc * 64 + i * 16 + lm;
      offB[kk][i] = 16384 + rowb * 64 + (((kk * 4 + quad) ^ (rowb & 7)) * 8);
    }
  }

  // prologue: stage K-tiles 0 (buf0) and 1 (buf1); wait tile0 only (vmcnt(6))
  #pragma unroll
  for (int it = 0; it < 4; ++it) async16(sA[it], smem + dA[it]);
  #pragma unroll
  for (int it = 0; it < 2; ++it) async16(sB[it], smem + dB[it]);
  #pragma unroll
  for (int it = 0; it < 4; ++it) async16(sA[it] + 64, smem + 24576 + dA[it]);
  #pragma unroll
  for (int it = 0; it < 2; ++it) async16(sB[it] + 64, smem + 24576 + dB[it]);
  asm volatile("s_waitcnt vmcnt(6)" ::: "memory");
  __builtin_amdgcn_s_barrier();

  int cb = 0;                                   // buffer of current tile
  for (int tt = 0; tt < 16; ++tt) {
    u16* base = smem + cb * 24576;
    int pb = cb + 2; if (pb >= 3) pb -= 3;      // buffer for tile tt+2
    u16* pbase = smem + pb * 24576;
    const int kg = (tt + 2) * 64;
    const bool pf = (tt + 2 < 16);
    frag8 a[4], b[4];

    // ---- phase 0 (k-half 0): reads || stage-half0 -> bar -> MFMA -> bar ----
    #pragma unroll
    for (int i = 0; i < 4; ++i) a[i] = *(const frag8*)(base + offA[0][i]);
    #pragma unroll
    for (int j = 0; j < 4; ++j) b[j] = *(const frag8*)(base + offB[0][j]);
    if (pf) {
      async16(sA[0] + kg, pbase + dA[0]);
      async16(sA[1] + kg, pbase + dA[1]);
      async16(sB[0] + kg, pbase + dB[0]);
    }
    __builtin_amdgcn_s_barrier();
    asm volatile("s_waitcnt lgkmcnt(0)" ::: "memory");
    __builtin_amdgcn_s_setprio(1);
    #pragma unroll
    for (int j = 0; j < 4; ++j)
      #pragma unroll
      for (int i = 0; i < 4; ++i)
        acc[i][j] = MFMA_BF16(a[i], b[j], acc[i][j]);
    __builtin_amdgcn_s_setprio(0);
    __builtin_amdgcn_s_barrier();

    // ---- phase 1 (k-half 1): reads || stage-half1 -> bar -> MFMA -> vmcnt -> bar ----
    #pragma unroll
    for (int i = 0; i < 4; ++i) a[i] = *(const frag8*)(base + offA[1][i]);
    #pragma unroll
    for (int j = 0; j < 4; ++j) b[j] = *(const frag8*)(base + offB[1][j]);
    if (pf) {
      async16(sA[2] + kg, pbase + dA[2]);
      async16(sA[3] + kg, pbase + dA[3]);
      async16(sB[1] + kg, pbase + dB[1]);
    }
    __builtin_amdgcn_s_barrier();
    asm volatile("s_waitcnt lgkmcnt(0)" ::: "memory");
    __builtin_amdgcn_s_setprio(1);
    #pragma unroll
    for (int j = 0; j < 4; ++j)
      #pragma unroll
      for (int i = 0; i < 4; ++i)
        acc[i][j] = MFMA_BF16(a[i], b[j], acc[i][j]);
    __builtin_amdgcn_s_setprio(0);
    // counted wait: tile tt+1 done, tile tt+2's 6 loads stay in flight
    if (pf) { asm volatile("s_waitcnt vmcnt(6)" ::: "memory"); }
    else    { asm volatile("s_waitcnt vmcnt(0)" ::: "memory"); }
    __builtin_amdgcn_s_barrier();

    cb = cb + 1; if (cb >= 3) cb = 0;
  }
}

// ---------------- fused QKV GEMM: B = [Wq;Wk;Wv] as [3072][1024] ----------------
// grid 768 = 32 m-tiles x 24 n-tiles = 3 perfect rounds of 256 CUs; each block's
// n-tile lies in exactly one of Q/K/V (z = n0>>10) -> single epilogue per block.
__global__ __launch_bounds__(512, 2) void k_gemm_qkv(
    const u16* __restrict__ xb, const u16* __restrict__ Wt,
    u16* __restrict__ Qg, u16* __restrict__ Kg, u16* __restrict__ Vtg) {
  __shared__ __attribute__((aligned(16))) u16 smem[73728];  // 3 x 48KB = 144KB
  const int bid = blockIdx.x;
  const int wgid = (bid & 7) * 96 + (bid >> 3);   // XCD-bijective (768 % 8 == 0)
  const int mt = wgid / 24, nt_ = wgid - mt * 24; // n fastest: A-panel L2 reuse
  const int m0 = mt * 256, n0 = nt_ * 128;
  f32x4 acc[4][4] = {};
  gemm_core_256x128(xb, Wt, m0, n0, smem, acc);

  const int t = threadIdx.x, lane = t & 63, wv = t >> 6;
  const int lm = lane & 15, quad = lane >> 4;
  const int wr = wv >> 1, wc = wv & 1;
  const int z = n0 >> 10, nz = n0 & 1023;

  if (z < 2) {
    // Q (pre-scaled) / K scatter to [b,h,n,64]
    u16* tgt = z ? Kg : Qg;
    const float sc = z ? 1.0f : SMSCALE;
    #pragma unroll
    for (int i = 0; i < 4; ++i)
      #pragma unroll
      for (int j = 0; j < 4; ++j) {
        const int col = nz + wc * 64 + j * 16 + lm;
        const int h = col >> 6, d = col & 63;
        #pragma unroll
        for (int reg = 0; reg < 4; ++reg) {
          const int row = m0 + wr * 64 + i * 16 + quad * 4 + reg;
          const int bb = row >> 11, nn = row & 2047;
          tgt[(((size_t)bb * 16 + h) * 2048 + nn) * 64 + d] = f2bf(acc[i][j][reg] * sc);
        }
      }
  } else {
    // V: transpose 256 tokens x 128 d-cols (2 heads) through LDS -> Vtg [bh][d][n]
    u16* T = smem;                               // [128][264] u16, reuse (all reads done)
    #pragma unroll
    for (int i = 0; i < 4; ++i)
      #pragma unroll
      for (int j = 0; j < 4; ++j) {
        const int rT = wc * 64 + j * 16 + lm;    // d within tile (0..127)
        #pragma unroll
        for (int reg = 0; reg < 4; ++reg) {
          const int cT = wr * 64 + i * 16 + quad * 4 + reg; // token local (0..255)
          T[rT * 264 + cT] = f2bf(acc[i][j][reg]);
        }
      }
    __syncthreads();
    const int bb = m0 >> 11, nn0 = m0 & 2047, h0 = nz >> 6;
    #pragma unroll
    for (int p = 0; p < 8; ++p) {
      int chunk = p * 512 + t;                   // 4096 frag8 chunks
      int r = chunk >> 5, tk = (chunk & 31) * 8; // r: d-row 0..127, tk: token*8
      frag8 v = *(const frag8*)(T + r * 264 + tk);
      *(frag8*)(Vtg + (((size_t)bb * 16 + h0 + (r >> 6)) * 64 + (r & 63)) * 2048 +
                nn0 + tk) = v;
    }
  }
}

// ---------------- flash attention (causal): 4 q-tiles per block, VALU diet ----------------
// R7 diagnosis: VALU-bound (VALUBusy 50% vs MfmaUtil 17.5%); ocml exp2f fixup and
// 3-op bf16 packs were ~3x the intrinsic VALU cost. R8: raw v_exp_f32, 1-op trunc
// pack, b64 Ps writes, hoisted addressing. Register budget ~200 -> (256,2);
// WRITE_SIZE is the spill tripwire (R3/R4 lesson).
__global__ __launch_bounds__(256, 2) void k_attn(const u16* __restrict__ Qg,
                                                 const u16* __restrict__ Kg,
                                                 const u16* __restrict__ Vtg,
                                                 u16* __restrict__ ctx) {
  __shared__ __attribute__((aligned(16))) u16 Ks[2][64 * 64];    // swizzled, dbuf
  __shared__ __attribute__((aligned(16))) u16 Vts[2][64 * 64];   // [d][key], swizzled, dbuf
  __shared__ __attribute__((aligned(16))) u16 Ps[4 * 16 * 72];
  // grid 512: bid = i*64 + bh_hi*8 + bh_lo -> bid%8 == bh%8 (XCD-stable per bh)
  const int bid = blockIdx.x;
  const int ib = bid >> 6;                       // 0..7
  const int bh = ((bid >> 3) & 7) * 8 + (bid & 7);
  const int qts[4] = {2 * ib, 2 * ib + 1, 30 - 2 * ib, 31 - 2 * ib};  // ascending
  const int t = threadIdx.x, lane = t & 63, wv = t >> 6;
  const int lm = lane & 15, quad = lane >> 4;
  const int b = bh >> 4, h = bh & 15;
  u16* const PsW = Ps + wv * (16 * 72);

  frag8 aq[4][2];
  #pragma unroll
  for (int qa = 0; qa < 4; ++qa) {
    const u16* qp = Qg + ((size_t)bh * 2048 + qts[qa] * 64 + wv * 16 + lm) * 64 + quad * 8;
    aq[qa][0] = *(const frag8*)(qp);
    aq[qa][1] = *(const frag8*)(qp + 32);
  }
  f32x4 o[4][4] = {};
  float l[4] = {0.f, 0.f, 0.f, 0.f};
  const int nst = 32 - 2 * ib;                   // staged tiles = qt_max+1

  // hoisted staging source pointers (advance by constant per kt)
  const u16* ksrc[2]; const u16* vsrc[2];
  #pragma unroll
  for (int it = 0; it < 2; ++it) {
    int chunk = it * 256 + t;
    int r = chunk >> 3, c = chunk & 7;
    int sc = (c ^ (r & 7)) * 8;
    ksrc[it] = Kg  + ((size_t)bh * 2048 + r) * 64 + sc;   // += 4096 per kt
    vsrc[it] = Vtg + ((size_t)bh * 64 + r) * 2048 + sc;   // += 64 per kt
  }
  // hoisted LDS fragment offsets (identical pattern for K and V tiles)
  int offs[8];
  #pragma unroll
  for (int x = 0; x < 4; ++x)
    #pragma unroll
    for (int y = 0; y < 2; ++y)
      offs[x * 2 + y] = (x * 16 + lm) * 64 + (((y * 4 + quad) ^ (lm & 7)) * 8);

  auto stage = [&](int kt, int buf) {
    #pragma unroll
    for (int it = 0; it < 2; ++it) {
      async16(ksrc[it] + (size_t)kt * 4096, &Ks[buf][(it * 256 + wv * 64) * 8]);
      async16(vsrc[it] + (size_t)kt * 64,   &Vts[buf][(it * 256 + wv * 64) * 8]);
    }
  };

  stage(0, 0);
  for (int kt0 = 0; kt0 < nst; ++kt0) {
    const int cur = kt0 & 1;
    __syncthreads();                             // loads(cur) done; prior compute done
    if (kt0 + 1 < nst) stage(kt0 + 1, cur ^ 1);  // overlap next staging with compute

    // hoist K-frags once, reuse for all active q-tiles
    frag8 kf[8];
    #pragma unroll
    for (int i = 0; i < 8; ++i) kf[i] = *(const frag8*)(&Ks[cur][offs[i]]);

    uint32_t pk[4][8];
    #pragma unroll
    for (int qa = 0; qa < 4; ++qa) {
      if (qts[qa] < kt0) continue;               // wave-uniform
      f32x4 s[4];
      #pragma unroll
      for (int kt = 0; kt < 4; ++kt) {
        f32x4 z = {0.f, 0.f, 0.f, 0.f};
        z = MFMA_BF16(kf[kt * 2 + 0], aq[qa][0], z);
        z = MFMA_BF16(kf[kt * 2 + 1], aq[qa][1], z);
        s[kt] = z;
      }
      if (kt0 == qts[qa]) {                      // diagonal tile mask
        #pragma unroll
        for (int kt = 0; kt < 4; ++kt)
          #pragma unroll
          for (int rg = 0; rg < 4; ++rg)
            if (kt * 16 + quad * 4 + rg > wv * 16 + lm) s[kt][rg] = -3.0e38f;
      }
      float rs = 0.f;
      #pragma unroll
      for (int kt = 0; kt < 4; ++kt) {
        float p0 = EXP2R(s[kt][0]);              // Q pre-scaled by 1/sqrt(d)*log2(e)
        float p1 = EXP2R(s[kt][1]);
        float p2 = EXP2R(s[kt][2]);
        float p3 = EXP2R(s[kt][3]);
        rs += (p0 + p1) + (p2 + p3);
        pk[qa][kt * 2 + 0] = pack_bf16_trunc(p0, p1);
        pk[qa][kt * 2 + 1] = pack_bf16_trunc(p2, p3);
      }
      l[qa] += rs;
    }

    // hoist V-frags once, reuse for all active q-tiles
    frag8 vf[8];
    #pragma unroll
    for (int i = 0; i < 8; ++i) vf[i] = *(const frag8*)(&Vts[cur][offs[i]]);

    #pragma unroll
    for (int qa = 0; qa < 4; ++qa) {
      if (qts[qa] < kt0) continue;
      #pragma unroll
      for (int kt = 0; kt < 4; ++kt) {
        u32x2 w; w.x = pk[qa][kt * 2 + 0]; w.y = pk[qa][kt * 2 + 1];
        *(u32x2*)(PsW + lm * 72 + kt * 16 + quad * 4) = w;
      }
      #pragma unroll
      for (int ks = 0; ks < 2; ++ks) {
        frag8 bp = *(const frag8*)(PsW + lm * 72 + ks * 32 + quad * 8);
        #pragma unroll
        for (int dt = 0; dt < 4; ++dt)
          o[qa][dt] = MFMA_BF16(vf[dt * 2 + ks], bp, o[qa][dt]);
      }
    }
  }

  // epilogues: reduce l across quads, normalize, transpose O^T->[q][d] via PsW, 16B stores
  #pragma unroll
  for (int qa = 0; qa < 4; ++qa) {
    float lv = l[qa];
    lv += __shfl_xor(lv, 16);
    lv += __shfl_xor(lv, 32);
    const float inv = 1.0f / lv;
    #pragma unroll
    for (int dt = 0; dt < 4; ++dt) {
      *(uint32_t*)(PsW + lm * 72 + dt * 16 + quad * 4)     = pack_bf16(o[qa][dt][0] * inv, o[qa][dt][1] * inv);
      *(uint32_t*)(PsW + lm * 72 + dt * 16 + quad * 4 + 2) = pack_bf16(o[qa][dt][2] * inv, o[qa][dt][3] * inv);
    }
    const int rr = lane >> 2, cc = (lane & 3) * 8;
    const size_t row = (size_t)b * 2048 + qts[qa] * 64 + wv * 16 + rr;
    #pragma unroll
    for (int half = 0; half < 2; ++half) {
      frag8 vo = *(const frag8*)(PsW + rr * 72 + cc + half * 32);
      *(frag8*)(ctx + row * 1024 + h * 64 + cc + half * 32) = vo;
    }
  }
}

// ---------------- output projection GEMM (+bias, fp32 out), same pipelined core ----------------
__global__ __launch_bounds__(512, 2) void k_gemm_out(
    const u16* __restrict__ ctx, const u16* __restrict__ Wot,
    const float* __restrict__ bo, float* __restrict__ out) {
  __shared__ __attribute__((aligned(16))) u16 smem[73728];
  const int bid = blockIdx.x;
  const int wgid = (bid & 7) * 32 + (bid >> 3);   // XCD-bijective (256 % 8 == 0)
  const int m0 = (wgid >> 3) * 256, n0 = (wgid & 7) * 128;
  f32x4 acc[4][4] = {};
  gemm_core_256x128(ctx, Wot, m0, n0, smem, acc);

  const int t = threadIdx.x, lane = t & 63, wv = t >> 6;
  const int lm = lane & 15, quad = lane >> 4;
  const int wr = wv >> 1, wc = wv & 1;
  #pragma unroll
  for (int i = 0; i < 4; ++i)
    #pragma unroll
    for (int j = 0; j < 4; ++j) {
      const int col = n0 + wc * 64 + j * 16 + lm;
      const float bias = bo[col];
      #pragma unroll
      for (int reg = 0; reg < 4; ++reg) {
        const int row = m0 + wr * 64 + i * 16 + quad * 4 + reg;
        out[(size_t)row * 1024 + col] = acc[i][j][reg] + bias;
      }
    }
}

extern "C" void kernel_launch(void* const* d_in, const int* in_sizes, int n_in,
                              void* d_out, int out_size, void* d_ws, size_t ws_size,
                              hipStream_t stream) {
  const float* x  = (const float*)d_in[0];
  const float* Wq = (const float*)d_in[1];
  const float* Wk = (const float*)d_in[2];
  const float* Wv = (const float*)d_in[3];
  const float* Wo = (const float*)d_in[4];
  const float* bo = (const float*)d_in[5];
  float* out = (float*)d_out;
  char* ws = (char*)d_ws;

  u16* xb   = (u16*)(ws);                          // 16 MB
  u16* Wqt  = (u16*)(ws + ((size_t)16 << 20));     //  2 MB each; Wqt/Wkt/Wvt contiguous
  u16* Wkt  = (u16*)(ws + ((size_t)18 << 20));     //  -> fused B matrix [3072][1024]
  u16* Wvt  = (u16*)(ws + ((size_t)20 << 20));
  u16* Wot  = (u16*)(ws + ((size_t)22 << 20));
  u16* Qg   = (u16*)(ws + ((size_t)24 << 20));     // 16 MB [b,h,n,64] (pre-scaled)
  u16* Kg   = (u16*)(ws + ((size_t)40 << 20));     // 16 MB [b,h,n,64]
  u16* Vtg  = (u16*)(ws + ((size_t)56 << 20));     // 16 MB [b,h,64,n]
  u16* ctxb = (u16*)(ws + ((size_t)72 << 20));     // 16 MB

  k_convert_x<<<8192, 256, 0, stream>>>((const float4*)x, xb);
  k_transpose_w4<<<dim3(16, 16, 4), 256, 0, stream>>>(Wq, Wk, Wv, Wo, Wqt, Wkt, Wvt, Wot);
  k_gemm_qkv<<<768, 512, 0, stream>>>(xb, Wqt, Qg, Kg, Vtg);
  k_attn<<<512, 256, 0, stream>>>(Qg, Kg, Vtg, ctxb);
  k_gemm_out<<<256, 512, 0, stream>>>(ctxb, Wot, bo, out);
}

// Round 3
// 235.433 us; speedup vs baseline: 1.0381x; 1.0381x over previous
//
#include <hip/hip_runtime.h>
#include <stdint.h>

typedef unsigned short u16;
typedef __attribute__((ext_vector_type(8))) short frag8;   // 8 bf16 in 4 VGPRs
typedef __attribute__((ext_vector_type(4))) float f32x4;
typedef __attribute__((ext_vector_type(4))) unsigned short u16x4;
typedef __attribute__((ext_vector_type(2))) unsigned int u32x2;

#define MFMA_BF16(a,b,c) __builtin_amdgcn_mfma_f32_16x16x32_bf16((a),(b),(c),0,0,0)
#define SMSCALE 0.18033688011112042f  /* (1/sqrt(64)) * log2(e) */
#define EXP2R(x) __builtin_amdgcn_exp2f(x)   /* raw v_exp_f32, no ocml fixup */

__device__ __forceinline__ u16 f2bf(float f) {
  union { float f; uint32_t u; } c; c.f = f;
  uint32_t u = c.u;
  uint32_t r = (u + 0x7fffu + ((u >> 16) & 1u)) >> 16;
  return (u16)r;
}

// pack two floats' bf16 (round-half-up) into one u32: low=a, high=b
__device__ __forceinline__ uint32_t pack_bf16(float a, float b) {
  uint32_t au = __float_as_uint(a) + 0x8000u;
  uint32_t bu = __float_as_uint(b) + 0x8000u;
  return __builtin_amdgcn_perm(bu, au, 0x07060302u);
}
// truncating pack (1 instr): P in [0,1], proportional bias cancels in O=SumpV/Sump
__device__ __forceinline__ uint32_t pack_bf16_trunc(float a, float b) {
  return __builtin_amdgcn_perm(__float_as_uint(b), __float_as_uint(a), 0x07060302u);
}

__device__ __forceinline__ void async16(const void* g, void* l) {
  __builtin_amdgcn_global_load_lds((const __attribute__((address_space(1))) void*)g,
                                   (__attribute__((address_space(3))) void*)l,
                                   16, 0, 0);
}

// ---------------- convert x (fp32 -> bf16) ----------------
__global__ __launch_bounds__(256) void k_convert_x(const float4* __restrict__ x,
                                                   u16* __restrict__ xb) {
  int i = blockIdx.x * 256 + threadIdx.x;
  float4 v = x[i];
  u16x4 o;
  o.x = f2bf(v.x); o.y = f2bf(v.y); o.z = f2bf(v.z); o.w = f2bf(v.w);
  *(u16x4*)(xb + (size_t)i * 4) = o;
}

// ---------------- transpose all 4 W (fp32 [k][n] -> bf16 [n][k]) ----------------
__global__ __launch_bounds__(256) void k_transpose_w4(
    const float* __restrict__ W0, const float* __restrict__ W1,
    const float* __restrict__ W2, const float* __restrict__ W3,
    u16* __restrict__ D0, u16* __restrict__ D1,
    u16* __restrict__ D2, u16* __restrict__ D3) {
  __shared__ float tile[64][65];
  const int z = blockIdx.z;
  const float* src = (z == 0) ? W0 : (z == 1) ? W1 : (z == 2) ? W2 : W3;
  u16* dst = (z == 0) ? D0 : (z == 1) ? D1 : (z == 2) ? D2 : D3;
  const int bx = blockIdx.x * 64;  // k base
  const int by = blockIdx.y * 64;  // n base
  const int t = threadIdx.x;
  const int tc = (t & 15) * 4;
  const int tr = t >> 4;
  #pragma unroll
  for (int p = 0; p < 4; ++p) {
    int r = tr + p * 16;
    float4 v = *(const float4*)(src + (size_t)(bx + r) * 1024 + by + tc);
    tile[r][tc + 0] = v.x; tile[r][tc + 1] = v.y;
    tile[r][tc + 2] = v.z; tile[r][tc + 3] = v.w;
  }
  __syncthreads();
  #pragma unroll
  for (int p = 0; p < 4; ++p) {
    int r = tr + p * 16;
    u16x4 o;
    o.x = f2bf(tile[tc + 0][r]);
    o.y = f2bf(tile[tc + 1][r]);
    o.z = f2bf(tile[tc + 2][r]);
    o.w = f2bf(tile[tc + 3][r]);
    *(u16x4*)(dst + (size_t)(by + r) * 1024 + bx + tc) = o;
  }
}

// ---------------- BK=32 counted-vmcnt pipelined GEMM core ----------------
// R1 post-mortem: per-wave 64x64 (512 B LDS/MFMA) + 1 blk/CU + coarse phases = 31%.
// R2/R3: per-wave 128x64 (375 B/MFMA, the m201/HK wave shape), BK=32 triple-buffer
// (small LDS -> 2+ blocks/CU for TLP), counted vmcnt(L) once per tile (never 0 in
// the loop, depth-2-tile prefetch covers HBM latency), setprio around MFMA.
// BK=32 bonus: an MFMA fragment read (16 rows x full 32-k) is a CONTIGUOUS 1 KB
// block -> full-LDS-BW by construction (8 lanes per 4-bank group, 8 distinct
// addrs = 8 cyc = 1024B/128B minimum); staging is linear; zero swizzle.
template<int BM, int BN, int WM, int WN>
__device__ __forceinline__ void gemm_core32(
    const u16* __restrict__ Ag,   // [M][1024] bf16, rows m0..m0+BM-1
    const u16* __restrict__ Bg,   // [N][1024] bf16 (n-major), rows n0..n0+BN-1
    int m0, int n0, u16* smem,
    f32x4 (&acc)[BM / (WM * 16)][BN / (WN * 16)]) {
  constexpr int WAVES = WM * WN;
  constexpr int MF = BM / (WM * 16), NF = BN / (WN * 16);
  constexpr int AI = BM / 16 / WAVES;      // A staging instrs per thread per tile
  constexpr int BI = BN / 16 / WAVES;      // B staging instrs per thread per tile
  constexpr int L  = AI + BI;              // per-wave vmcnt ledger: L loads/tile
  constexpr int L0 = (L + 1) / 2;
  constexpr int TILE = (BM + BN) * 32;     // u16 per buffer
  constexpr int BOFF = BM * 32;            // u16 offset of B region
  const int t = threadIdx.x, lane = t & 63, wv = t >> 6;
  const int lm = lane & 15, quad = lane >> 4;
  const int wr = wv / WN, wc = wv % WN;

  // staging sources (per-lane global addr, advance by 32 u16 per K-tile) and
  // wave-uniform LDS dsts (HW appends lane*16)
  const u16* srcs[L];
  int dsts[L];
  #pragma unroll
  for (int i = 0; i < AI; ++i) {
    int w = wv * AI + i;                   // wave-instr id: 1 KB linear slab each
    int chunk = w * 64 + lane;             // 16B chunk: row = chunk>>2, c = chunk&3
    srcs[i] = Ag + (size_t)(m0 + (chunk >> 2)) * 1024 + (chunk & 3) * 8;
    dsts[i] = w * 512;
  }
  #pragma unroll
  for (int i = 0; i < BI; ++i) {
    int w = wv * BI + i;
    int chunk = w * 64 + lane;
    srcs[AI + i] = Bg + (size_t)(n0 + (chunk >> 2)) * 1024 + (chunk & 3) * 8;
    dsts[AI + i] = BOFF + w * 512;
  }
  // fragment read offsets (u16): row-major [rows][32], lane reads k=quad*8..+8
  int offA[MF], offB[NF];
  #pragma unroll
  for (int i = 0; i < MF; ++i) offA[i] = (wr * (BM / WM) + i * 16 + lm) * 32 + quad * 8;
  #pragma unroll
  for (int j = 0; j < NF; ++j) offB[j] = BOFF + (wc * (BN / WN) + j * 16 + lm) * 32 + quad * 8;

  // prologue: stage tiles 0 -> buf0, 1 -> buf1; wait tile0 only (tile1 in flight)
  #pragma unroll
  for (int i = 0; i < L; ++i) async16(srcs[i], smem + dsts[i]);
  #pragma unroll
  for (int i = 0; i < L; ++i) async16(srcs[i] + 32, smem + TILE + dsts[i]);
  asm volatile("s_waitcnt vmcnt(%0)" :: "n"(L) : "memory");
  __builtin_amdgcn_s_barrier();

  int cb = 0;
  for (int tt = 0; tt < 32; ++tt) {
    u16* base = smem + cb * TILE;
    int pb = cb + 2; if (pb >= 3) pb -= 3;   // buffer for tile tt+2 (freed at tt-1)
    u16* pbase = smem + pb * TILE;
    const int kadv = (tt + 2) * 32;
    const bool pf = (tt + 2 < 32);
    frag8 a[MF], b[NF];

    // ---- phase 0: A-half0 + all B reads || stage first L0 -> bar -> MFMA ----
    #pragma unroll
    for (int i = 0; i < MF / 2; ++i) a[i] = *(const frag8*)(base + offA[i]);
    #pragma unroll
    for (int j = 0; j < NF; ++j) b[j] = *(const frag8*)(base + offB[j]);
    if (pf) {
      #pragma unroll
      for (int i = 0; i < L0; ++i) async16(srcs[i] + kadv, pbase + dsts[i]);
    }
    __builtin_amdgcn_s_barrier();
    asm volatile("s_waitcnt lgkmcnt(0)" ::: "memory");
    __builtin_amdgcn_s_setprio(1);
    #pragma unroll
    for (int j = 0; j < NF; ++j)
      #pragma unroll
      for (int i = 0; i < MF / 2; ++i)
        acc[i][j] = MFMA_BF16(a[i], b[j], acc[i][j]);
    __builtin_amdgcn_s_setprio(0);
    __builtin_amdgcn_s_barrier();

    // ---- phase 1: A-half1 reads || stage rest -> bar -> MFMA -> vmcnt(L) ----
    #pragma unroll
    for (int i = MF / 2; i < MF; ++i) a[i] = *(const frag8*)(base + offA[i]);
    if (pf) {
      #pragma unroll
      for (int i = L0; i < L; ++i) async16(srcs[i] + kadv, pbase + dsts[i]);
    }
    __builtin_amdgcn_s_barrier();
    asm volatile("s_waitcnt lgkmcnt(0)" ::: "memory");
    __builtin_amdgcn_s_setprio(1);
    #pragma unroll
    for (int j = 0; j < NF; ++j)
      #pragma unroll
      for (int i = MF / 2; i < MF; ++i)
        acc[i][j] = MFMA_BF16(a[i], b[j], acc[i][j]);
    __builtin_amdgcn_s_setprio(0);
    // counted wait: tile tt+1 landed, tile tt+2's L loads stay in flight
    if (pf) { asm volatile("s_waitcnt vmcnt(%0)" :: "n"(L) : "memory"); }
    else    { asm volatile("s_waitcnt vmcnt(0)" ::: "memory"); }
    __builtin_amdgcn_s_barrier();

    cb = cb + 1; if (cb >= 3) cb = 0;
  }
}

// ---------------- fused QKV GEMM: B = [Wq;Wk;Wv] as [3072][1024] ----------------
// BM=128 BN=256, 4 waves (1x4), per-wave 128x64; 72 KB LDS -> 2 blocks/CU.
// grid 768 = 64 m x 12 n; n-tile of 256 lies in exactly one of Q/K/V.
__global__ __launch_bounds__(256, 2) void k_gemm_qkv(
    const u16* __restrict__ xb, const u16* __restrict__ Wt,
    u16* __restrict__ Qg, u16* __restrict__ Kg, u16* __restrict__ Vtg) {
  __shared__ __attribute__((aligned(16))) u16 smem[3 * (128 + 256) * 32];  // 72 KB
  const int bid = blockIdx.x;
  const int wgid = (bid & 7) * 96 + (bid >> 3);  // XCD-bijective (768 % 8 == 0)
  const int mt = wgid & 63, nt = wgid >> 6;      // m fastest: B-panel stays hot in L2
  const int m0 = mt * 128, n0g = nt * 256;
  f32x4 acc[8][4] = {};
  gemm_core32<128, 256, 1, 4>(xb, Wt, m0, n0g, smem, acc);

  const int t = threadIdx.x, lane = t & 63, wv = t >> 6;
  const int lm = lane & 15, quad = lane >> 4;
  const int wc = wv & 3;                         // WN=4
  const int z = n0g >> 10, nz = n0g & 1023;

  if (z < 2) {
    // Q (pre-scaled) / K scatter to [b,h,n,64]
    u16* tgt = z ? Kg : Qg;
    const float sc = z ? 1.0f : SMSCALE;
    #pragma unroll
    for (int i = 0; i < 8; ++i)
      #pragma unroll
      for (int j = 0; j < 4; ++j) {
        const int col = nz + wc * 64 + j * 16 + lm;
        const int h = col >> 6, d = col & 63;
        #pragma unroll
        for (int reg = 0; reg < 4; ++reg) {
          const int row = m0 + i * 16 + quad * 4 + reg;
          const int bb = row >> 11, nn = row & 2047;
          tgt[(((size_t)bb * 16 + h) * 2048 + nn) * 64 + d] = f2bf(acc[i][j][reg] * sc);
        }
      }
  } else {
    // V: transpose 128 tokens x 256 d-cols (4 heads) through LDS -> Vtg [bh][d][n]
    u16* T = smem;                               // [256][136] u16, reuse post-loop
    #pragma unroll
    for (int i = 0; i < 8; ++i)
      #pragma unroll
      for (int j = 0; j < 4; ++j) {
        const int rT = wc * 64 + j * 16 + lm;    // d within tile (0..255)
        #pragma unroll
        for (int reg = 0; reg < 4; ++reg) {
          const int cT = i * 16 + quad * 4 + reg;  // token local (0..127)
          T[rT * 136 + cT] = f2bf(acc[i][j][reg]);
        }
      }
    __syncthreads();
    const int bb = m0 >> 11, nn0 = m0 & 2047;
    #pragma unroll
    for (int p = 0; p < 16; ++p) {
      int chunk = p * 256 + t;                   // 4096 frag8 chunks
      int rT = chunk >> 4, tk = (chunk & 15) * 8;
      frag8 v = *(const frag8*)(T + rT * 136 + tk);
      const int col = nz + rT;
      *(frag8*)(Vtg + (((size_t)bb * 16 + (col >> 6)) * 64 + (col & 63)) * 2048 +
                nn0 + tk) = v;
    }
  }
}

// ---------------- flash attention (causal): 4 q-tiles per block, VALU diet ----------------
// R7 diagnosis: VALU-bound (VALUBusy 50% vs MfmaUtil 17.5%); ocml exp2f fixup and
// 3-op bf16 packs were ~3x the intrinsic VALU cost. R8: raw v_exp_f32, 1-op trunc
// pack, b64 Ps writes, hoisted addressing. Register budget ~200 -> (256,2);
// WRITE_SIZE is the spill tripwire (R3/R4 lesson).
__global__ __launch_bounds__(256, 2) void k_attn(const u16* __restrict__ Qg,
                                                 const u16* __restrict__ Kg,
                                                 const u16* __restrict__ Vtg,
                                                 u16* __restrict__ ctx) {
  __shared__ __attribute__((aligned(16))) u16 Ks[2][64 * 64];    // swizzled, dbuf
  __shared__ __attribute__((aligned(16))) u16 Vts[2][64 * 64];   // [d][key], swizzled, dbuf
  __shared__ __attribute__((aligned(16))) u16 Ps[4 * 16 * 72];
  // grid 512: bid = i*64 + bh_hi*8 + bh_lo -> bid%8 == bh%8 (XCD-stable per bh)
  const int bid = blockIdx.x;
  const int ib = bid >> 6;                       // 0..7
  const int bh = ((bid >> 3) & 7) * 8 + (bid & 7);
  const int qts[4] = {2 * ib, 2 * ib + 1, 30 - 2 * ib, 31 - 2 * ib};  // ascending
  const int t = threadIdx.x, lane = t & 63, wv = t >> 6;
  const int lm = lane & 15, quad = lane >> 4;
  const int b = bh >> 4, h = bh & 15;
  u16* const PsW = Ps + wv * (16 * 72);

  frag8 aq[4][2];
  #pragma unroll
  for (int qa = 0; qa < 4; ++qa) {
    const u16* qp = Qg + ((size_t)bh * 2048 + qts[qa] * 64 + wv * 16 + lm) * 64 + quad * 8;
    aq[qa][0] = *(const frag8*)(qp);
    aq[qa][1] = *(const frag8*)(qp + 32);
  }
  f32x4 o[4][4] = {};
  float l[4] = {0.f, 0.f, 0.f, 0.f};
  const int nst = 32 - 2 * ib;                   // staged tiles = qt_max+1

  // hoisted staging source pointers (advance by constant per kt)
  const u16* ksrc[2]; const u16* vsrc[2];
  #pragma unroll
  for (int it = 0; it < 2; ++it) {
    int chunk = it * 256 + t;
    int r = chunk >> 3, c = chunk & 7;
    int sc = (c ^ (r & 7)) * 8;
    ksrc[it] = Kg  + ((size_t)bh * 2048 + r) * 64 + sc;   // += 4096 per kt
    vsrc[it] = Vtg + ((size_t)bh * 64 + r) * 2048 + sc;   // += 64 per kt
  }
  // hoisted LDS fragment offsets (identical pattern for K and V tiles)
  int offs[8];
  #pragma unroll
  for (int x = 0; x < 4; ++x)
    #pragma unroll
    for (int y = 0; y < 2; ++y)
      offs[x * 2 + y] = (x * 16 + lm) * 64 + (((y * 4 + quad) ^ (lm & 7)) * 8);

  auto stage = [&](int kt, int buf) {
    #pragma unroll
    for (int it = 0; it < 2; ++it) {
      async16(ksrc[it] + (size_t)kt * 4096, &Ks[buf][(it * 256 + wv * 64) * 8]);
      async16(vsrc[it] + (size_t)kt * 64,   &Vts[buf][(it * 256 + wv * 64) * 8]);
    }
  };

  stage(0, 0);
  for (int kt0 = 0; kt0 < nst; ++kt0) {
    const int cur = kt0 & 1;
    __syncthreads();                             // loads(cur) done; prior compute done
    if (kt0 + 1 < nst) stage(kt0 + 1, cur ^ 1);  // overlap next staging with compute

    // hoist K-frags once, reuse for all active q-tiles
    frag8 kf[8];
    #pragma unroll
    for (int i = 0; i < 8; ++i) kf[i] = *(const frag8*)(&Ks[cur][offs[i]]);

    uint32_t pk[4][8];
    #pragma unroll
    for (int qa = 0; qa < 4; ++qa) {
      if (qts[qa] < kt0) continue;               // wave-uniform
      f32x4 s[4];
      #pragma unroll
      for (int kt = 0; kt < 4; ++kt) {
        f32x4 z = {0.f, 0.f, 0.f, 0.f};
        z = MFMA_BF16(kf[kt * 2 + 0], aq[qa][0], z);
        z = MFMA_BF16(kf[kt * 2 + 1], aq[qa][1], z);
        s[kt] = z;
      }
      if (kt0 == qts[qa]) {                      // diagonal tile mask
        #pragma unroll
        for (int kt = 0; kt < 4; ++kt)
          #pragma unroll
          for (int rg = 0; rg < 4; ++rg)
            if (kt * 16 + quad * 4 + rg > wv * 16 + lm) s[kt][rg] = -3.0e38f;
      }
      float rs = 0.f;
      #pragma unroll
      for (int kt = 0; kt < 4; ++kt) {
        float p0 = EXP2R(s[kt][0]);              // Q pre-scaled by 1/sqrt(d)*log2(e)
        float p1 = EXP2R(s[kt][1]);
        float p2 = EXP2R(s[kt][2]);
        float p3 = EXP2R(s[kt][3]);
        rs += (p0 + p1) + (p2 + p3);
        pk[qa][kt * 2 + 0] = pack_bf16_trunc(p0, p1);
        pk[qa][kt * 2 + 1] = pack_bf16_trunc(p2, p3);
      }
      l[qa] += rs;
    }

    // hoist V-frags once, reuse for all active q-tiles
    frag8 vf[8];
    #pragma unroll
    for (int i = 0; i < 8; ++i) vf[i] = *(const frag8*)(&Vts[cur][offs[i]]);

    #pragma unroll
    for (int qa = 0; qa < 4; ++qa) {
      if (qts[qa] < kt0) continue;
      #pragma unroll
      for (int kt = 0; kt < 4; ++kt) {
        u32x2 w; w.x = pk[qa][kt * 2 + 0]; w.y = pk[qa][kt * 2 + 1];
        *(u32x2*)(PsW + lm * 72 + kt * 16 + quad * 4) = w;
      }
      #pragma unroll
      for (int ks = 0; ks < 2; ++ks) {
        frag8 bp = *(const frag8*)(PsW + lm * 72 + ks * 32 + quad * 8);
        #pragma unroll
        for (int dt = 0; dt < 4; ++dt)
          o[qa][dt] = MFMA_BF16(vf[dt * 2 + ks], bp, o[qa][dt]);
      }
    }
  }

  // epilogues: reduce l across quads, normalize, transpose O^T->[q][d] via PsW, 16B stores
  #pragma unroll
  for (int qa = 0; qa < 4; ++qa) {
    float lv = l[qa];
    lv += __shfl_xor(lv, 16);
    lv += __shfl_xor(lv, 32);
    const float inv = 1.0f / lv;
    #pragma unroll
    for (int dt = 0; dt < 4; ++dt) {
      *(uint32_t*)(PsW + lm * 72 + dt * 16 + quad * 4)     = pack_bf16(o[qa][dt][0] * inv, o[qa][dt][1] * inv);
      *(uint32_t*)(PsW + lm * 72 + dt * 16 + quad * 4 + 2) = pack_bf16(o[qa][dt][2] * inv, o[qa][dt][3] * inv);
    }
    const int rr = lane >> 2, cc = (lane & 3) * 8;
    const size_t row = (size_t)b * 2048 + qts[qa] * 64 + wv * 16 + rr;
    #pragma unroll
    for (int half = 0; half < 2; ++half) {
      frag8 vo = *(const frag8*)(PsW + rr * 72 + cc + half * 32);
      *(frag8*)(ctx + row * 1024 + h * 64 + cc + half * 32) = vo;
    }
  }
}

// ---------------- output projection GEMM (+bias, fp32 out), same pipelined core ----------------
// BM=128 BN=128, 4 waves (2x2), per-wave 64x64; 48 KB LDS -> up to 3 blocks/CU.
__global__ __launch_bounds__(256, 3) void k_gemm_out(
    const u16* __restrict__ ctx, const u16* __restrict__ Wot,
    const float* __restrict__ bo, float* __restrict__ out) {
  __shared__ __attribute__((aligned(16))) u16 smem[3 * (128 + 128) * 32];  // 48 KB
  const int bid = blockIdx.x;
  const int wgid = (bid & 7) * 64 + (bid >> 3);  // XCD-bijective (512 % 8 == 0)
  const int mt = wgid & 63, nt = wgid >> 6;
  const int m0 = mt * 128, n0 = nt * 128;
  f32x4 acc[4][4] = {};
  gemm_core32<128, 128, 2, 2>(ctx, Wot, m0, n0, smem, acc);

  const int t = threadIdx.x, lane = t & 63, wv = t >> 6;
  const int lm = lane & 15, quad = lane >> 4;
  const int wr = wv >> 1, wc = wv & 1;
  #pragma unroll
  for (int i = 0; i < 4; ++i)
    #pragma unroll
    for (int j = 0; j < 4; ++j) {
      const int col = n0 + wc * 64 + j * 16 + lm;
      const float bias = bo[col];
      #pragma unroll
      for (int reg = 0; reg < 4; ++reg) {
        const int row = m0 + wr * 64 + i * 16 + quad * 4 + reg;
        out[(size_t)row * 1024 + col] = acc[i][j][reg] + bias;
      }
    }
}

extern "C" void kernel_launch(void* const* d_in, const int* in_sizes, int n_in,
                              void* d_out, int out_size, void* d_ws, size_t ws_size,
                              hipStream_t stream) {
  const float* x  = (const float*)d_in[0];
  const float* Wq = (const float*)d_in[1];
  const float* Wk = (const float*)d_in[2];
  const float* Wv = (const float*)d_in[3];
  const float* Wo = (const float*)d_in[4];
  const float* bo = (const float*)d_in[5];
  float* out = (float*)d_out;
  char* ws = (char*)d_ws;

  u16* xb   = (u16*)(ws);                          // 16 MB
  u16* Wqt  = (u16*)(ws + ((size_t)16 << 20));     //  2 MB each; Wqt/Wkt/Wvt contiguous
  u16* Wkt  = (u16*)(ws + ((size_t)18 << 20));     //  -> fused B matrix [3072][1024]
  u16* Wvt  = (u16*)(ws + ((size_t)20 << 20));
  u16* Wot  = (u16*)(ws + ((size_t)22 << 20));
  u16* Qg   = (u16*)(ws + ((size_t)24 << 20));     // 16 MB [b,h,n,64] (pre-scaled)
  u16* Kg   = (u16*)(ws + ((size_t)40 << 20));     // 16 MB [b,h,n,64]
  u16* Vtg  = (u16*)(ws + ((size_t)56 << 20));     // 16 MB [b,h,64,n]
  u16* ctxb = (u16*)(ws + ((size_t)72 << 20));     // 16 MB

  k_convert_x<<<8192, 256, 0, stream>>>((const float4*)x, xb);
  k_transpose_w4<<<dim3(16, 16, 4), 256, 0, stream>>>(Wq, Wk, Wv, Wo, Wqt, Wkt, Wvt, Wot);
  k_gemm_qkv<<<768, 256, 0, stream>>>(xb, Wqt, Qg, Kg, Vtg);
  k_attn<<<512, 256, 0, stream>>>(Qg, Kg, Vtg, ctxb);
  k_gemm_out<<<512, 256, 0, stream>>>(ctxb, Wot, bo, out);
}

// Round 4
// 218.003 us; speedup vs baseline: 1.1211x; 1.0800x over previous
//
#include <hip/hip_runtime.h>
#include <stdint.h>

typedef unsigned short u16;
typedef __attribute__((ext_vector_type(8))) short frag8;   // 8 bf16 in 4 VGPRs
typedef __attribute__((ext_vector_type(4))) float f32x4;
typedef __attribute__((ext_vector_type(4))) unsigned short u16x4;
typedef __attribute__((ext_vector_type(2))) unsigned int u32x2;

#define MFMA_BF16(a,b,c) __builtin_amdgcn_mfma_f32_16x16x32_bf16((a),(b),(c),0,0,0)
#define SMSCALE 0.18033688011112042f  /* (1/sqrt(64)) * log2(e) */
#define EXP2R(x) __builtin_amdgcn_exp2f(x)   /* raw v_exp_f32, no ocml fixup */

__device__ __forceinline__ u16 f2bf(float f) {
  union { float f; uint32_t u; } c; c.f = f;
  uint32_t u = c.u;
  uint32_t r = (u + 0x7fffu + ((u >> 16) & 1u)) >> 16;
  return (u16)r;
}

// pack two floats' bf16 (round-half-up) into one u32: low=a, high=b
__device__ __forceinline__ uint32_t pack_bf16(float a, float b) {
  uint32_t au = __float_as_uint(a) + 0x8000u;
  uint32_t bu = __float_as_uint(b) + 0x8000u;
  return __builtin_amdgcn_perm(bu, au, 0x07060302u);
}
// truncating pack (1 instr): P in [0,1], proportional bias cancels in O=SumpV/Sump
__device__ __forceinline__ uint32_t pack_bf16_trunc(float a, float b) {
  return __builtin_amdgcn_perm(__float_as_uint(b), __float_as_uint(a), 0x07060302u);
}

__device__ __forceinline__ void async16(const void* g, void* l) {
  __builtin_amdgcn_global_load_lds((const __attribute__((address_space(1))) void*)g,
                                   (__attribute__((address_space(3))) void*)l,
                                   16, 0, 0);
}

// ---------------- fused prep: convert x (fp32->bf16) + transpose all 4 W ----------------
// R4: merged the two independent memory-bound prep kernels into one launch to
// remove a kernel-launch gap. Block-uniform branch; shared mem only used by the
// transpose path. blocks 0..8191 = convert, 8192..9215 = 1024 transpose tiles.
__global__ __launch_bounds__(256) void k_prep(
    const float4* __restrict__ x, u16* __restrict__ xb,
    const float* __restrict__ W0, const float* __restrict__ W1,
    const float* __restrict__ W2, const float* __restrict__ W3,
    u16* __restrict__ D0, u16* __restrict__ D1,
    u16* __restrict__ D2, u16* __restrict__ D3) {
  __shared__ float tile[64][65];
  if (blockIdx.x < 8192) {
    int i = blockIdx.x * 256 + threadIdx.x;
    float4 v = x[i];
    u16x4 o;
    o.x = f2bf(v.x); o.y = f2bf(v.y); o.z = f2bf(v.z); o.w = f2bf(v.w);
    *(u16x4*)(xb + (size_t)i * 4) = o;
    return;
  }
  const int id = blockIdx.x - 8192;              // 0..1023 = 16 x 16 x 4
  const int z = id & 3;
  const float* src = (z == 0) ? W0 : (z == 1) ? W1 : (z == 2) ? W2 : W3;
  u16* dst = (z == 0) ? D0 : (z == 1) ? D1 : (z == 2) ? D2 : D3;
  const int bx = ((id >> 2) & 15) * 64;  // k base
  const int by = (id >> 6) * 64;         // n base
  const int t = threadIdx.x;
  const int tc = (t & 15) * 4;
  const int tr = t >> 4;
  #pragma unroll
  for (int p = 0; p < 4; ++p) {
    int r = tr + p * 16;
    float4 v = *(const float4*)(src + (size_t)(bx + r) * 1024 + by + tc);
    tile[r][tc + 0] = v.x; tile[r][tc + 1] = v.y;
    tile[r][tc + 2] = v.z; tile[r][tc + 3] = v.w;
  }
  __syncthreads();
  #pragma unroll
  for (int p = 0; p < 4; ++p) {
    int r = tr + p * 16;
    u16x4 o;
    o.x = f2bf(tile[tc + 0][r]);
    o.y = f2bf(tile[tc + 1][r]);
    o.z = f2bf(tile[tc + 2][r]);
    o.w = f2bf(tile[tc + 3][r]);
    *(u16x4*)(dst + (size_t)(by + r) * 1024 + bx + tc) = o;
  }
}

// ---------------- fused QKV GEMM: 128x128 tile x 3 outputs, BK=64, swizzled LDS ----------------
// R4 revert: this exact configuration measured 57.5 us / 896 TF / MfmaUtil 35% /
// FETCH 33 MB. Key properties (R1/R3 post-mortems): grid 512 = exactly 2
// blocks/CU -> fully co-resident, in-flight fetch sharing (FETCH 33 MB vs 86-103
// when broken); BK=64 row stride 128 B + XOR swizzle -> conflict-free ds_read_b128
// (196K vs 4.9M at BK=32/stride-64); m97-class 2-barrier loop = ~36% structure
// ceiling. Two counted-vmcnt phase-split attempts both landed ~31-33% — do not
// retry without the exact verified m201 interleave.
__global__ __launch_bounds__(256, 2) void k_gemm_qkv(const u16* __restrict__ xb,
    const u16* __restrict__ Wqt, const u16* __restrict__ Wkt, const u16* __restrict__ Wvt,
    u16* __restrict__ Qg, u16* __restrict__ Kg, u16* __restrict__ Vtg) {
  __shared__ __attribute__((aligned(16))) u16 smem[4 * 128 * 64];  // A + 3xB, 64 KB
  u16* T = smem;                       // 64x136 u16 transpose buffer, reused post-loop
  const int m0 = blockIdx.x * 128, n0 = blockIdx.y * 128;
  const int t = threadIdx.x, lane = t & 63, wv = t >> 6;
  const int lm = lane & 15, quad = lane >> 4;
  const int wr = wv >> 1, wc = wv & 1;
  f32x4 acc[3][4][4] = {};

  for (int k0 = 0; k0 < 1024; k0 += 64) {
    #pragma unroll
    for (int it = 0; it < 4; ++it) {
      int chunk = it * 256 + t;                    // 0..1023 16B chunks
      int r = chunk >> 3;
      int sc = ((chunk & 7) ^ (r & 7)) * 8;
      async16(xb + (size_t)(m0 + r) * 1024 + k0 + sc,
              smem + (size_t)(it * 256 + wv * 64) * 8);
    }
    #pragma unroll
    for (int z = 0; z < 3; ++z) {
      const u16* Bt = (z == 0) ? Wqt : (z == 1) ? Wkt : Wvt;
      #pragma unroll
      for (int it = 0; it < 4; ++it) {
        int chunk = it * 256 + t;
        int r = chunk >> 3;
        int sc = ((chunk & 7) ^ (r & 7)) * 8;
        async16(Bt + (size_t)(n0 + r) * 1024 + k0 + sc,
                smem + (size_t)((z + 1) * 1024 + it * 256 + wv * 64) * 8);
      }
    }
    __syncthreads();
    #pragma unroll
    for (int kk = 0; kk < 2; ++kk) {
      frag8 a[4];
      #pragma unroll
      for (int i = 0; i < 4; ++i) {
        int row = wr * 64 + i * 16 + lm;
        a[i] = *(const frag8*)(smem + row * 64 + (((kk * 4 + quad) ^ (row & 7)) * 8));
      }
      #pragma unroll
      for (int z = 0; z < 3; ++z) {
        #pragma unroll
        for (int j = 0; j < 4; ++j) {
          int row = wc * 64 + j * 16 + lm;
          frag8 b = *(const frag8*)(smem + (z + 1) * 8192 + row * 64 +
                                    (((kk * 4 + quad) ^ (row & 7)) * 8));
          #pragma unroll
          for (int i = 0; i < 4; ++i)
            acc[z][i][j] = MFMA_BF16(a[i], b, acc[z][i][j]);
        }
      }
    }
    __syncthreads();
  }

  // epilogue: Q (pre-scaled) and K scatter to [b,h,n,64]
  #pragma unroll
  for (int z = 0; z < 2; ++z) {
    u16* tgt = z ? Kg : Qg;
    const float sc = z ? 1.0f : SMSCALE;
    #pragma unroll
    for (int i = 0; i < 4; ++i)
      #pragma unroll
      for (int j = 0; j < 4; ++j) {
        const int col = n0 + wc * 64 + j * 16 + lm;
        const int h = col >> 6, d = col & 63;
        #pragma unroll
        for (int reg = 0; reg < 4; ++reg) {
          const int row = m0 + wr * 64 + i * 16 + quad * 4 + reg;
          const int bb = row >> 11, nn = row & 2047;
          tgt[(((size_t)bb * 16 + h) * 2048 + nn) * 64 + d] = f2bf(acc[z][i][j][reg] * sc);
        }
      }
  }
  // epilogue: V transposed through LDS -> Vtg [bh][d][n], two 64-col passes
  {
    const int bb = m0 >> 11, nn0 = m0 & 2047;
    const int h0 = n0 >> 6;
    #pragma unroll
    for (int p = 0; p < 2; ++p) {
      if (wc == p) {
        #pragma unroll
        for (int i = 0; i < 4; ++i)
          #pragma unroll
          for (int j = 0; j < 4; ++j) {
            const int rT = j * 16 + lm;                         // d within pass (0..63)
            #pragma unroll
            for (int reg = 0; reg < 4; ++reg) {
              const int cT = wr * 64 + i * 16 + quad * 4 + reg; // token local (0..127)
              T[rT * 136 + cT] = f2bf(acc[2][i][j][reg]);
            }
          }
      }
      __syncthreads();
      #pragma unroll
      for (int cc = 0; cc < 4; ++cc) {
        int chunk = cc * 256 + t;
        int r = chunk >> 4, tk = (chunk & 15) * 8;
        frag8 v = *(const frag8*)(T + r * 136 + tk);
        *(frag8*)(Vtg + (((size_t)bb * 16 + h0 + p) * 64 + r) * 2048 + nn0 + tk) = v;
      }
      __syncthreads();
    }
  }
}

// ---------------- flash attention (causal): 4 q-tiles per block, VALU diet ----------------
// R7 diagnosis: VALU-bound (VALUBusy 50% vs MfmaUtil 17.5%); ocml exp2f fixup and
// 3-op bf16 packs were ~3x the intrinsic VALU cost. R8: raw v_exp_f32, 1-op trunc
// pack, b64 Ps writes, hoisted addressing. Register budget ~200 -> (256,2);
// WRITE_SIZE is the spill tripwire (R3/R4 lesson).
// R4 note: per-CU staging = 2 blocks x 16 KB per kt-period ~= 42 B/cyc vs 56 B/cyc
// per-CU L2 ceiling -> near L2-BW-bound too. Any restructure must INCREASE K/V
// sharing per stage (e.g. 8 waves/stage), never decrease it (V-direct-read or
// q-tile split would quadruple/double staging traffic — computed, not tried).
__global__ __launch_bounds__(256, 2) void k_attn(const u16* __restrict__ Qg,
                                                 const u16* __restrict__ Kg,
                                                 const u16* __restrict__ Vtg,
                                                 u16* __restrict__ ctx) {
  __shared__ __attribute__((aligned(16))) u16 Ks[2][64 * 64];    // swizzled, dbuf
  __shared__ __attribute__((aligned(16))) u16 Vts[2][64 * 64];   // [d][key], swizzled, dbuf
  __shared__ __attribute__((aligned(16))) u16 Ps[4 * 16 * 72];
  // grid 512: bid = i*64 + bh_hi*8 + bh_lo -> bid%8 == bh%8 (XCD-stable per bh)
  const int bid = blockIdx.x;
  const int ib = bid >> 6;                       // 0..7
  const int bh = ((bid >> 3) & 7) * 8 + (bid & 7);
  const int qts[4] = {2 * ib, 2 * ib + 1, 30 - 2 * ib, 31 - 2 * ib};  // ascending
  const int t = threadIdx.x, lane = t & 63, wv = t >> 6;
  const int lm = lane & 15, quad = lane >> 4;
  const int b = bh >> 4, h = bh & 15;
  u16* const PsW = Ps + wv * (16 * 72);

  frag8 aq[4][2];
  #pragma unroll
  for (int qa = 0; qa < 4; ++qa) {
    const u16* qp = Qg + ((size_t)bh * 2048 + qts[qa] * 64 + wv * 16 + lm) * 64 + quad * 8;
    aq[qa][0] = *(const frag8*)(qp);
    aq[qa][1] = *(const frag8*)(qp + 32);
  }
  f32x4 o[4][4] = {};
  float l[4] = {0.f, 0.f, 0.f, 0.f};
  const int nst = 32 - 2 * ib;                   // staged tiles = qt_max+1

  // hoisted staging source pointers (advance by constant per kt)
  const u16* ksrc[2]; const u16* vsrc[2];
  #pragma unroll
  for (int it = 0; it < 2; ++it) {
    int chunk = it * 256 + t;
    int r = chunk >> 3, c = chunk & 7;
    int sc = (c ^ (r & 7)) * 8;
    ksrc[it] = Kg  + ((size_t)bh * 2048 + r) * 64 + sc;   // += 4096 per kt
    vsrc[it] = Vtg + ((size_t)bh * 64 + r) * 2048 + sc;   // += 64 per kt
  }
  // hoisted LDS fragment offsets (identical pattern for K and V tiles)
  int offs[8];
  #pragma unroll
  for (int x = 0; x < 4; ++x)
    #pragma unroll
    for (int y = 0; y < 2; ++y)
      offs[x * 2 + y] = (x * 16 + lm) * 64 + (((y * 4 + quad) ^ (lm & 7)) * 8);

  auto stage = [&](int kt, int buf) {
    #pragma unroll
    for (int it = 0; it < 2; ++it) {
      async16(ksrc[it] + (size_t)kt * 4096, &Ks[buf][(it * 256 + wv * 64) * 8]);
      async16(vsrc[it] + (size_t)kt * 64,   &Vts[buf][(it * 256 + wv * 64) * 8]);
    }
  };

  stage(0, 0);
  for (int kt0 = 0; kt0 < nst; ++kt0) {
    const int cur = kt0 & 1;
    __syncthreads();                             // loads(cur) done; prior compute done
    if (kt0 + 1 < nst) stage(kt0 + 1, cur ^ 1);  // overlap next staging with compute

    // hoist K-frags once, reuse for all active q-tiles
    frag8 kf[8];
    #pragma unroll
    for (int i = 0; i < 8; ++i) kf[i] = *(const frag8*)(&Ks[cur][offs[i]]);

    uint32_t pk[4][8];
    #pragma unroll
    for (int qa = 0; qa < 4; ++qa) {
      if (qts[qa] < kt0) continue;               // wave-uniform
      f32x4 s[4];
      #pragma unroll
      for (int kt = 0; kt < 4; ++kt) {
        f32x4 z = {0.f, 0.f, 0.f, 0.f};
        z = MFMA_BF16(kf[kt * 2 + 0], aq[qa][0], z);
        z = MFMA_BF16(kf[kt * 2 + 1], aq[qa][1], z);
        s[kt] = z;
      }
      if (kt0 == qts[qa]) {                      // diagonal tile mask
        #pragma unroll
        for (int kt = 0; kt < 4; ++kt)
          #pragma unroll
          for (int rg = 0; rg < 4; ++rg)
            if (kt * 16 + quad * 4 + rg > wv * 16 + lm) s[kt][rg] = -3.0e38f;
      }
      float rs = 0.f;
      #pragma unroll
      for (int kt = 0; kt < 4; ++kt) {
        float p0 = EXP2R(s[kt][0]);              // Q pre-scaled by 1/sqrt(d)*log2(e)
        float p1 = EXP2R(s[kt][1]);
        float p2 = EXP2R(s[kt][2]);
        float p3 = EXP2R(s[kt][3]);
        rs += (p0 + p1) + (p2 + p3);
        pk[qa][kt * 2 + 0] = pack_bf16_trunc(p0, p1);
        pk[qa][kt * 2 + 1] = pack_bf16_trunc(p2, p3);
      }
      l[qa] += rs;
    }

    // hoist V-frags once, reuse for all active q-tiles
    frag8 vf[8];
    #pragma unroll
    for (int i = 0; i < 8; ++i) vf[i] = *(const frag8*)(&Vts[cur][offs[i]]);

    #pragma unroll
    for (int qa = 0; qa < 4; ++qa) {
      if (qts[qa] < kt0) continue;
      #pragma unroll
      for (int kt = 0; kt < 4; ++kt) {
        u32x2 w; w.x = pk[qa][kt * 2 + 0]; w.y = pk[qa][kt * 2 + 1];
        *(u32x2*)(PsW + lm * 72 + kt * 16 + quad * 4) = w;
      }
      #pragma unroll
      for (int ks = 0; ks < 2; ++ks) {
        frag8 bp = *(const frag8*)(PsW + lm * 72 + ks * 32 + quad * 8);
        #pragma unroll
        for (int dt = 0; dt < 4; ++dt)
          o[qa][dt] = MFMA_BF16(vf[dt * 2 + ks], bp, o[qa][dt]);
      }
    }
  }

  // epilogues: reduce l across quads, normalize, transpose O^T->[q][d] via PsW, 16B stores
  #pragma unroll
  for (int qa = 0; qa < 4; ++qa) {
    float lv = l[qa];
    lv += __shfl_xor(lv, 16);
    lv += __shfl_xor(lv, 32);
    const float inv = 1.0f / lv;
    #pragma unroll
    for (int dt = 0; dt < 4; ++dt) {
      *(uint32_t*)(PsW + lm * 72 + dt * 16 + quad * 4)     = pack_bf16(o[qa][dt][0] * inv, o[qa][dt][1] * inv);
      *(uint32_t*)(PsW + lm * 72 + dt * 16 + quad * 4 + 2) = pack_bf16(o[qa][dt][2] * inv, o[qa][dt][3] * inv);
    }
    const int rr = lane >> 2, cc = (lane & 3) * 8;
    const size_t row = (size_t)b * 2048 + qts[qa] * 64 + wv * 16 + rr;
    #pragma unroll
    for (int half = 0; half < 2; ++half) {
      frag8 vo = *(const frag8*)(PsW + rr * 72 + cc + half * 32);
      *(frag8*)(ctx + row * 1024 + h * 64 + cc + half * 32) = vo;
    }
  }
}

// ---------------- output projection GEMM (+bias, fp32 out), BK=64, swizzled ----------------
__global__ __launch_bounds__(256) void k_gemm_out(const u16* __restrict__ ctx,
    const u16* __restrict__ Wot, const float* __restrict__ bo, float* __restrict__ out) {
  __shared__ __attribute__((aligned(16))) u16 As[128 * 64];
  __shared__ __attribute__((aligned(16))) u16 Bs[128 * 64];
  const int m0 = blockIdx.x * 128, n0 = blockIdx.y * 128;
  const int t = threadIdx.x, lane = t & 63, wv = t >> 6;
  const int lm = lane & 15, quad = lane >> 4;
  const int wr = wv >> 1, wc = wv & 1;
  f32x4 acc[4][4] = {};
  for (int k0 = 0; k0 < 1024; k0 += 64) {
    #pragma unroll
    for (int it = 0; it < 4; ++it) {
      int chunk = it * 256 + t;
      int r = chunk >> 3;
      int sc = ((chunk & 7) ^ (r & 7)) * 8;
      async16(ctx + (size_t)(m0 + r) * 1024 + k0 + sc, As + (size_t)(it * 256 + wv * 64) * 8);
      async16(Wot + (size_t)(n0 + r) * 1024 + k0 + sc, Bs + (size_t)(it * 256 + wv * 64) * 8);
    }
    __syncthreads();
    #pragma unroll
    for (int kk = 0; kk < 2; ++kk) {
      frag8 a[4];
      #pragma unroll
      for (int i = 0; i < 4; ++i) {
        int row = wr * 64 + i * 16 + lm;
        a[i] = *(const frag8*)(As + row * 64 + (((kk * 4 + quad) ^ (row & 7)) * 8));
      }
      #pragma unroll
      for (int j = 0; j < 4; ++j) {
        int row = wc * 64 + j * 16 + lm;
        frag8 b = *(const frag8*)(Bs + row * 64 + (((kk * 4 + quad) ^ (row & 7)) * 8));
        #pragma unroll
        for (int i = 0; i < 4; ++i)
          acc[i][j] = MFMA_BF16(a[i], b, acc[i][j]);
      }
    }
    __syncthreads();
  }
  #pragma unroll
  for (int i = 0; i < 4; ++i)
    #pragma unroll
    for (int j = 0; j < 4; ++j) {
      const int col = n0 + wc * 64 + j * 16 + lm;
      const float bias = bo[col];
      #pragma unroll
      for (int reg = 0; reg < 4; ++reg) {
        const int row = m0 + wr * 64 + i * 16 + quad * 4 + reg;
        out[(size_t)row * 1024 + col] = acc[i][j][reg] + bias;
      }
    }
}

extern "C" void kernel_launch(void* const* d_in, const int* in_sizes, int n_in,
                              void* d_out, int out_size, void* d_ws, size_t ws_size,
                              hipStream_t stream) {
  const float* x  = (const float*)d_in[0];
  const float* Wq = (const float*)d_in[1];
  const float* Wk = (const float*)d_in[2];
  const float* Wv = (const float*)d_in[3];
  const float* Wo = (const float*)d_in[4];
  const float* bo = (const float*)d_in[5];
  float* out = (float*)d_out;
  char* ws = (char*)d_ws;

  u16* xb   = (u16*)(ws);                          // 16 MB
  u16* Wqt  = (u16*)(ws + ((size_t)16 << 20));     //  2 MB each
  u16* Wkt  = (u16*)(ws + ((size_t)18 << 20));
  u16* Wvt  = (u16*)(ws + ((size_t)20 << 20));
  u16* Wot  = (u16*)(ws + ((size_t)22 << 20));
  u16* Qg   = (u16*)(ws + ((size_t)24 << 20));     // 16 MB [b,h,n,64] (pre-scaled)
  u16* Kg   = (u16*)(ws + ((size_t)40 << 20));     // 16 MB [b,h,n,64]
  u16* Vtg  = (u16*)(ws + ((size_t)56 << 20));     // 16 MB [b,h,64,n]
  u16* ctxb = (u16*)(ws + ((size_t)72 << 20));     // 16 MB

  k_prep<<<9216, 256, 0, stream>>>((const float4*)x, xb, Wq, Wk, Wv, Wo,
                                   Wqt, Wkt, Wvt, Wot);
  k_gemm_qkv<<<dim3(64, 8), 256, 0, stream>>>(xb, Wqt, Wkt, Wvt, Qg, Kg, Vtg);
  k_attn<<<512, 256, 0, stream>>>(Qg, Kg, Vtg, ctxb);
  k_gemm_out<<<dim3(64, 8), 256, 0, stream>>>(ctxb, Wot, bo, out);
}